// Round 4
// baseline (914.061 us; speedup 1.0000x reference)
//
#include <hip/hip_runtime.h>
#include <math.h>

#define DIMK 2048
#define NEMB 16384
#define NB 256
#define NR2 1536          // 256*6 neighbor rows
#define NBLK 128          // n-blocks in sims gemm
#define INV_BETA 20.0f
#define NEG_INF (-3.0e38f)

typedef short short8 __attribute__((ext_vector_type(8)));
typedef float f32x4 __attribute__((ext_vector_type(4)));
typedef const __attribute__((address_space(1))) unsigned int* gas_ptr;
typedef __attribute__((address_space(3))) unsigned int* las_ptr;

__device__ __forceinline__ void gl_lds16(const void* g, void* l) {
  __builtin_amdgcn_global_load_lds((gas_ptr)g, (las_ptr)l, 16, 0, 0);
}

__device__ __forceinline__ unsigned short f2bf(float f) {
  unsigned u = __float_as_uint(f);
  u += 0x7fffu + ((u >> 16) & 1u);
  return (unsigned short)(u >> 16);
}

__device__ __forceinline__ void ins6(float x, float v[6]) {
  if (x > v[5]) {
    v[5] = x;
#pragma unroll
    for (int j = 5; j > 0; j--) {
      if (v[j] > v[j - 1]) { float tmp = v[j]; v[j] = v[j - 1]; v[j - 1] = tmp; }
    }
  }
}

// top-6 insert with (value desc, index asc) tie-break — matches jax top_k order
__device__ __forceinline__ void ins6i(float x, int xi, float v[6], int vi[6]) {
  if (x > v[5] || (x == v[5] && xi < vi[5])) {
    v[5] = x; vi[5] = xi;
#pragma unroll
    for (int j = 5; j > 0; j--) {
      if (v[j] > v[j - 1] || (v[j] == v[j - 1] && vi[j] < vi[j - 1])) {
        float tv = v[j]; v[j] = v[j - 1]; v[j - 1] = tv;
        int ti = vi[j]; vi[j] = vi[j - 1]; vi[j - 1] = ti;
      }
    }
  }
}

__global__ __launch_bounds__(256) void cvt_kernel(const float* __restrict__ src,
                                                  unsigned short* __restrict__ dst, int n4) {
  int i = blockIdx.x * 256 + threadIdx.x;
  if (i < n4) {
    float4 f = ((const float4*)src)[i];
    ushort4 o;
    o.x = f2bf(f.x); o.y = f2bf(f.y); o.z = f2bf(f.z); o.w = f2bf(f.w);
    ((ushort4*)dst)[i] = o;
  }
}

// Staging subtile = [16 rows x 32 k] bf16 = 1 KB.  DMA lane l fetches global
// (row = l>>2, kseg = (l&3) XOR ((l>>2)&3)); LDS dst is HW-fixed base + l*16.
// => each 64B global line lands as 64B CONTIGUOUS LDS write (conflict-free;
// the old row=l&15 map made every line a 4-way bank conflict = the 7.6e7).
// Fragment read for lane l: offset ((l&15)*4 + ((l>>4)^(l&3)))*16 B — a
// balanced bank permutation (<=2-way per phase).  BK=64: two k-halves per
// barrier pair, slots [h*NSUB + sub].
// MODE 0: C = X(256xK) * em^T -> logits*20 (fp32). tile 64x128, grid (128,4)
// MODE 1: C = em[nidx](1536xK) * em^T -> per-(row,128col) top-6 partials. tile 128x128
template <int MODE>
__global__ __launch_bounds__(256, 4) void gemm_kernel(
    const unsigned short* __restrict__ Abase, const unsigned short* __restrict__ Bbase,
    const int* __restrict__ nidx, float* __restrict__ outC, float* __restrict__ part6) {
  constexpr int MTILE = (MODE == 0) ? 64 : 128;
  constexpr int MI = 4;
  constexpr int NI = (MODE == 0) ? 2 : 4;
  constexpr int NSUB_A = MTILE / 16;   // 4 or 8
  constexpr int NSUB = NSUB_A + 8;     // subtiles per k-half: 12 or 16
  constexpr int NSLOT = NSUB * 2;      // BK=64 -> 24 or 32 slots
  constexpr int NA = NSLOT / 4;        // DMAs per wave: 6 or 8

  union SMemT {
    unsigned short st[NSLOT * 512];                        // 24 or 32 KB staging
    struct { float ct[32 * 133]; float p6[32 * 49]; } ep;  // 23.3 KB (MODE1 only)
  };
  __shared__ SMemT sm;
  __shared__ int rowIdxSh[128];
  int t = threadIdx.x;
  int lane = t & 63, wave = t >> 6;
  int quad = lane >> 4, l16 = lane & 15;
  int wr = (MODE == 0) ? 0 : (wave >> 1);
  int wc = (MODE == 0) ? wave : (wave & 1);
  int bn = blockIdx.x, bm = blockIdx.y;

  if constexpr (MODE == 1) {
    if (t < 128) rowIdxSh[t] = nidx[bm * 128 + t];
  }
  __syncthreads();

  const unsigned short* agp[NA];
  unsigned short* ldst[NA];
  {
    int r4 = lane >> 2;                    // row within subtile 0..15
    int kseg = (lane & 3) ^ (r4 & 3);      // xor-swizzled 16B-chunk
#pragma unroll
    for (int a = 0; a < NA; a++) {
      int s2 = wave + a * 4;               // slot 0..NSLOT-1
      int h = s2 / NSUB, sub = s2 % NSUB;  // k-half, subtile
      const unsigned short* basep;
      size_t goff;
      if (sub < NSUB_A) {
        int r = sub * 16 + r4;
        int grow = (MODE == 0) ? (bm * MTILE + r) : rowIdxSh[r];
        basep = Abase;
        goff = (size_t)grow * DIMK;
      } else {
        int r = (sub - NSUB_A) * 16 + r4;
        basep = Bbase;
        goff = (size_t)(bn * 128 + r) * DIMK;
      }
      agp[a] = basep + goff + h * 32 + kseg * 8;
      ldst[a] = &sm.st[s2 * 512];          // wave-uniform LDS base
    }
  }
  // fragment read offset (shorts): lane wants (row=l16, kseg=quad) of its subtile
  int rdoff = l16 * 32 + (quad ^ (lane & 3)) * 8;

  f32x4 acc[MI][NI];
#pragma unroll
  for (int mi = 0; mi < MI; mi++)
#pragma unroll
    for (int ni = 0; ni < NI; ni++) acc[mi][ni] = (f32x4)0.0f;

  for (int k0 = 0; k0 < DIMK; k0 += 64) {
    __syncthreads();   // previous iter's fragment reads complete
#pragma unroll
    for (int a = 0; a < NA; a++) gl_lds16(agp[a] + k0, ldst[a]);
    __syncthreads();   // drains vmcnt -> staged data visible
#pragma unroll
    for (int h = 0; h < 2; h++) {
      short8 af[MI], bfv[NI];
#pragma unroll
      for (int mi = 0; mi < MI; mi++)
        af[mi] = *(const short8*)&sm.st[(h * NSUB + wr * MI + mi) * 512 + rdoff];
#pragma unroll
      for (int ni = 0; ni < NI; ni++)
        bfv[ni] = *(const short8*)&sm.st[(h * NSUB + NSUB_A + wc * NI + ni) * 512 + rdoff];
#pragma unroll
      for (int mi = 0; mi < MI; mi++)
#pragma unroll
        for (int ni = 0; ni < NI; ni++)
          acc[mi][ni] =
              __builtin_amdgcn_mfma_f32_16x16x32_bf16(af[mi], bfv[ni], acc[mi][ni], 0, 0, 0);
    }
  }

  if constexpr (MODE == 0) {
#pragma unroll
    for (int mi = 0; mi < MI; mi++) {
      int row = bm * MTILE + mi * 16 + quad * 4;
#pragma unroll
      for (int ni = 0; ni < NI; ni++) {
        int col = bn * 128 + wave * 32 + ni * 16 + l16;
#pragma unroll
        for (int rr = 0; rr < 4; rr++)
          outC[(size_t)(row + rr) * NEMB + col] = acc[mi][ni][rr] * INV_BETA;
      }
    }
  } else {
    __syncthreads();  // all LDS staging reads done before union reuse
#pragma unroll
    for (int ph = 0; ph < 4; ph++) {       // 32 tile-rows per phase
      int phwr = ph >> 1, phmi0 = (ph & 1) * 2;
      if (wr == phwr) {
#pragma unroll
        for (int mi2 = 0; mi2 < 2; mi2++) {
          int mi = phmi0 + mi2;
#pragma unroll
          for (int ni = 0; ni < 4; ni++)
#pragma unroll
            for (int rr = 0; rr < 4; rr++)
              sm.ep.ct[(mi2 * 16 + quad * 4 + rr) * 133 + wc * 64 + ni * 16 + l16] =
                  acc[mi][ni][rr];
        }
      }
      __syncthreads();
      {
        int srow = t & 31, sseg = t >> 5;   // 8 segs x 16 cols
        float v[6] = {NEG_INF, NEG_INF, NEG_INF, NEG_INF, NEG_INF, NEG_INF};
        const float* basep = &sm.ep.ct[srow * 133 + sseg * 16];
#pragma unroll
        for (int i = 0; i < 16; i++) ins6(basep[i], v);
#pragma unroll
        for (int j = 0; j < 6; j++) sm.ep.p6[srow * 49 + sseg * 6 + j] = v[j];
      }
      __syncthreads();
      if (t < 32) {
        float v[6] = {NEG_INF, NEG_INF, NEG_INF, NEG_INF, NEG_INF, NEG_INF};
        const float* pp = &sm.ep.p6[t * 49];
        for (int i = 0; i < 48; i++) ins6(pp[i], v);
        int rg = bm * 128 + ph * 32 + t;
        float* dst = part6 + ((size_t)rg * NBLK + bn) * 6;
#pragma unroll
        for (int j = 0; j < 6; j++) dst[j] = v[j];
      }
      __syncthreads();
    }
  }
}

// single-pass: per-thread top6(v,i) + online (max,sumexp), then LDS tree merge
__global__ __launch_bounds__(256) void rowstats_kernel(
    const float* __restrict__ logits, float* __restrict__ topv,
    int* __restrict__ topi, float* __restrict__ lse) {
  int m = blockIdx.x, t = threadIdx.x;
  const float* row = logits + (size_t)m * NEMB;
  float v6[6]; int i6[6];
#pragma unroll
  for (int j = 0; j < 6; j++) { v6[j] = NEG_INF; i6[j] = 0x7fffffff; }
  float mx = NEG_INF, sme = 0.f;
  for (int i = t; i < NEMB; i += 256) {
    float v = row[i];
    if (v > mx) { sme = sme * expf(mx - v) + 1.f; mx = v; }
    else sme += expf(v - mx);
    ins6i(v, i, v6, i6);
  }
  __shared__ float sv[256 * 6]; __shared__ int si[256 * 6];
  __shared__ float smx[256], ssm[256];
#pragma unroll
  for (int j = 0; j < 6; j++) { sv[t * 6 + j] = v6[j]; si[t * 6 + j] = i6[j]; }
  smx[t] = mx; ssm[t] = sme;
  __syncthreads();
  for (int s = 128; s > 0; s >>= 1) {
    if (t < s) {
      float mo = smx[t + s], lo = ssm[t + s];
      float mn = fmaxf(smx[t], mo);
      ssm[t] = ssm[t] * expf(smx[t] - mn) + lo * expf(mo - mn);
      smx[t] = mn;
#pragma unroll
      for (int j = 0; j < 6; j++) ins6i(sv[(t + s) * 6 + j], si[(t + s) * 6 + j], v6, i6);
#pragma unroll
      for (int j = 0; j < 6; j++) { sv[t * 6 + j] = v6[j]; si[t * 6 + j] = i6[j]; }
    }
    __syncthreads();
  }
  if (t == 0) {
    lse[m] = smx[0] + logf(ssm[0]);
#pragma unroll
    for (int j = 0; j < 6; j++) { topv[m * 6 + j] = v6[j]; topi[m * 6 + j] = i6[j]; }
  }
}

// exact fp32 dot: sa[r] = em[topi[r]] . em[anchor(m=r/6)]
__global__ __launch_bounds__(256) void sa_kernel(const float* __restrict__ em,
                                                 const int* __restrict__ topi,
                                                 float* __restrict__ sa) {
  int gid = blockIdx.x * 256 + threadIdx.x;
  int w = gid >> 6, lane = gid & 63;
  if (w >= NR2) return;
  int m = w / 6;
  int i = topi[w], a = topi[m * 6];
  const float* ei = em + (size_t)i * DIMK;
  const float* ea = em + (size_t)a * DIMK;
  float s = 0.f;
  for (int d = lane; d < DIMK; d += 64) s += ei[d] * ea[d];
#pragma unroll
  for (int off = 32; off > 0; off >>= 1) s += __shfl_down(s, off, 64);
  if (lane == 0) sa[w] = s;
}

// recip[r] = 1 iff anchor-sim >= 6th-largest of sims row r
// == (count of partial-top6 values strictly greater than sa) < 6
__global__ __launch_bounds__(256) void stage2_kernel(const float* __restrict__ part6,
                                                     const float* __restrict__ sa,
                                                     int* __restrict__ recip) {
  int gid = blockIdx.x * 256 + threadIdx.x;
  int w = gid >> 6, lane = gid & 63;
  if (w >= NR2) return;
  float s = sa[w];
  const float* p = part6 + (size_t)w * (NBLK * 6);
  int cnt = 0;
  for (int i = lane; i < NBLK * 6; i += 64) cnt += (p[i] > s) ? 1 : 0;
#pragma unroll
  for (int off = 32; off > 0; off >>= 1) cnt += __shfl_down(cnt, off, 64);
  if (lane == 0) recip[w] = (cnt < 6) ? 1 : 0;
}

__global__ __launch_bounds__(256) void final_kernel(
    const float* __restrict__ logits, const float* __restrict__ topv,
    const int* __restrict__ topi, const float* __restrict__ lse_arr,
    const int* __restrict__ recip, const int* __restrict__ targets,
    float* __restrict__ out) {
  int m = threadIdx.x;
  float lse = lse_arr[m];
  int tgt = targets[m];
  float tl = logits[(size_t)m * NEMB + tgt];
  float beta = 0.f, Ps = 0.f, nbp = 0.f;
  bool tin = false;
#pragma unroll
  for (int k = 0; k < 6; k++) {
    int idx = topi[m * 6 + k]; float v = topv[m * 6 + k];
    float p = expf(v - lse);
    if (idx == tgt) { tin = true; beta += (lse - v); Ps += p; }
    else if (recip[m * 6 + k]) { beta += 0.5f * (lse - v); Ps += p; nbp += p; }
  }
  if (!tin) { beta += (lse - tl); Ps += expf(tl - lse); }
  float alpha = 9.2103404f * (1.f - Ps) + 0.6931472f * nbp;
  __shared__ float sA[256], sB2[256];
  sA[m] = alpha; sB2[m] = beta;
  __syncthreads();
  for (int s = 128; s > 0; s >>= 1) {
    if (m < s) { sA[m] += sA[m + s]; sB2[m] += sB2[m + s]; }
    __syncthreads();
  }
  if (m == 0) { out[0] = 0.05f * sA[0] / 256.f; out[1] = sB2[0] / 256.f; }
}

extern "C" void kernel_launch(void* const* d_in, const int* in_sizes, int n_in,
                              void* d_out, int out_size, void* d_ws, size_t ws_size,
                              hipStream_t stream) {
  const float* x = (const float*)d_in[0];
  const float* em = (const float*)d_in[1];
  const int* targets = (const int*)d_in[2];
  char* ws = (char*)d_ws;
  unsigned short* em_bf = (unsigned short*)ws;                 // 67108864 B
  unsigned short* x_bf  = (unsigned short*)(ws + 67108864);    // 1048576 B
  float* logits = (float*)(ws + 68157440);                     // 16777216 B
  float* part6  = (float*)(ws + 84934656);                     // 4718592 B
  float* topv   = (float*)(ws + 89653248);                     // 6144 B
  int*   topi   = (int*)  (ws + 89659392);                     // 6144 B
  float* lse    = (float*)(ws + 89665536);                     // 1024 B
  float* sa     = (float*)(ws + 89666560);                     // 6144 B
  int*   recip  = (int*)  (ws + 89672704);                     // 6144 B

  cvt_kernel<<<dim3(32768), dim3(256), 0, stream>>>(em, em_bf, NEMB * DIMK / 4);
  cvt_kernel<<<dim3(512), dim3(256), 0, stream>>>(x, x_bf, NB * DIMK / 4);
  gemm_kernel<0><<<dim3(128, 4), dim3(256), 0, stream>>>(x_bf, em_bf, (const int*)nullptr,
                                                         logits, (float*)nullptr);
  rowstats_kernel<<<dim3(256), dim3(256), 0, stream>>>(logits, topv, topi, lse);
  sa_kernel<<<dim3(384), dim3(256), 0, stream>>>(em, topi, sa);
  gemm_kernel<1><<<dim3(128, 12), dim3(256), 0, stream>>>(em_bf, em_bf, topi,
                                                          (float*)nullptr, part6);
  stage2_kernel<<<dim3(384), dim3(256), 0, stream>>>(part6, sa, recip);
  final_kernel<<<dim3(1), dim3(256), 0, stream>>>(logits, topv, topi, lse, recip, targets,
                                                  (float*)d_out);
}

// Round 5
// 624.931 us; speedup vs baseline: 1.4627x; 1.4627x over previous
//
#include <hip/hip_runtime.h>
#include <math.h>
#include <type_traits>

#define DIMK 2048
#define NEMB 16384
#define NB 256
#define NR2 1536          // 256*6 neighbor rows
#define NBLK 128          // n-blocks
#define INV_BETA 20.0f
#define NEG_INF (-3.0e38f)

typedef short short8 __attribute__((ext_vector_type(8)));
typedef float f32x4 __attribute__((ext_vector_type(4)));
typedef const __attribute__((address_space(1))) unsigned int* gas_ptr;
typedef __attribute__((address_space(3))) unsigned int* las_ptr;

__device__ __forceinline__ void gl_lds16(const void* g, void* l) {
  __builtin_amdgcn_global_load_lds((gas_ptr)g, (las_ptr)l, 16, 0, 0);
}

__device__ __forceinline__ unsigned short f2bf(float f) {
  unsigned u = __float_as_uint(f);
  u += 0x7fffu + ((u >> 16) & 1u);
  return (unsigned short)(u >> 16);
}

__device__ __forceinline__ void ins6(float x, float v[6]) {
  if (x > v[5]) {
    v[5] = x;
#pragma unroll
    for (int j = 5; j > 0; j--) {
      if (v[j] > v[j - 1]) { float tmp = v[j]; v[j] = v[j - 1]; v[j - 1] = tmp; }
    }
  }
}

// top-6 insert with (value desc, index asc) tie-break — matches jax top_k order
__device__ __forceinline__ void ins6i(float x, int xi, float v[6], int vi[6]) {
  if (x > v[5] || (x == v[5] && xi < vi[5])) {
    v[5] = x; vi[5] = xi;
#pragma unroll
    for (int j = 5; j > 0; j--) {
      if (v[j] > v[j - 1] || (v[j] == v[j - 1] && vi[j] < vi[j - 1])) {
        float tv = v[j]; v[j] = v[j - 1]; v[j - 1] = tv;
        int ti = vi[j]; vi[j] = vi[j - 1]; vi[j - 1] = ti;
      }
    }
  }
}

__global__ __launch_bounds__(256) void cvt_kernel(const float* __restrict__ src,
                                                  unsigned short* __restrict__ dst, int n4) {
  int i = blockIdx.x * 256 + threadIdx.x;
  if (i < n4) {
    float4 f = ((const float4*)src)[i];
    ushort4 o;
    o.x = f2bf(f.x); o.y = f2bf(f.y); o.z = f2bf(f.z); o.w = f2bf(f.w);
    ((ushort4*)dst)[i] = o;
  }
}

// Staging subtile = [16 rows x 32 k] bf16 = 1 KB, fragment-contiguous: chunk for
// (row=lane&15, kseg=lane>>4) at byte offset lane*16. DMA LDS writes are always
// base+lane*16 contiguous (HW); fragment ds_read_b128 at base+lane*16 is
// conflict-free. SQ_LDS_BANK_CONFLICT residual ~7.6e7 is DMA-return port
// contention, proportional to staged bytes — intrinsic, not layout-fixable.
// BK=32, NA<=4 DMAs/wave: keeps address state in ~8 VGPRs (BK=64/NA=8 spilled
// to scratch -> 1.4 GB HBM traffic, R4 regression).
struct EpM0 {                       // logits gemm fused-stats epilogue (~31 KB)
  float ct[32 * 133];
  float p6v[32 * 8 * 6];
  int   p6i[32 * 8 * 6];
  float ms[32 * 8 * 2];
};
struct EpM1 {                       // sims gemm top-6 epilogue (~23.3 KB)
  float ct[32 * 133];
  float p6[32 * 49];
};

// MODE 0: C = X(256xK) * em^T * 20 -> per-(row,128col-block) top6(v,i) + (max,sumexp)
//         tile 64x128, grid (128,4)
// MODE 1: C = em[nidx](1536xK) * em^T -> per-(row,128col-block) top-6 partials
//         tile 128x128, grid (128,12)
template <int MODE>
__global__ __launch_bounds__(256, 4) void gemm_kernel(
    const unsigned short* __restrict__ Abase, const unsigned short* __restrict__ Bbase,
    const int* __restrict__ nidx, float* __restrict__ p1, float* __restrict__ p2,
    float* __restrict__ p3, float* __restrict__ p4) {
  constexpr int MTILE = (MODE == 0) ? 64 : 128;
  constexpr int MI = 4;
  constexpr int NI = (MODE == 0) ? 2 : 4;
  constexpr int NSUB_A = MTILE / 16;   // 4 or 8
  constexpr int NSUB = NSUB_A + 8;     // 12 or 16 subtiles
  constexpr int NA = NSUB / 4;         // 3 or 4 DMAs per wave per k-iter

  using Ep = typename std::conditional<MODE == 0, EpM0, EpM1>::type;
  union SMemT {
    unsigned short st[NSUB * 512];
    Ep ep;
  };
  __shared__ SMemT sm;
  __shared__ int rowIdxSh[128];
  int t = threadIdx.x;
  int lane = t & 63, wave = t >> 6;
  int quad = lane >> 4, l16 = lane & 15;
  int wr = (MODE == 0) ? 0 : (wave >> 1);
  int wc = (MODE == 0) ? wave : (wave & 1);
  int bn = blockIdx.x, bm = blockIdx.y;

  if constexpr (MODE == 1) {
    if (t < 128) rowIdxSh[t] = nidx[bm * 128 + t];
  }
  __syncthreads();

  const unsigned short* agp[NA];
  unsigned short* ldst[NA];
  {
    int seg = lane >> 4;
#pragma unroll
    for (int a = 0; a < NA; a++) {
      int s = wave + a * 4;
      const unsigned short* basep;
      size_t goff;
      if (s < NSUB_A) {
        int r = s * 16 + l16;
        int grow = (MODE == 0) ? (bm * MTILE + r) : rowIdxSh[r];
        basep = Abase;
        goff = (size_t)grow * DIMK;
      } else {
        int r = (s - NSUB_A) * 16 + l16;
        basep = Bbase;
        goff = (size_t)(bn * 128 + r) * DIMK;
      }
      agp[a] = basep + goff + seg * 8;
      ldst[a] = &sm.st[s * 512];      // wave-uniform LDS base
    }
  }

  f32x4 acc[MI][NI];
#pragma unroll
  for (int mi = 0; mi < MI; mi++)
#pragma unroll
    for (int ni = 0; ni < NI; ni++) acc[mi][ni] = (f32x4)0.0f;

  int lo = lane * 8;  // shorts: lane*16 bytes
  for (int k0 = 0; k0 < DIMK; k0 += 32) {
    __syncthreads();   // previous iter's fragment reads complete
#pragma unroll
    for (int a = 0; a < NA; a++) gl_lds16(agp[a] + k0, ldst[a]);
    __syncthreads();   // drains vmcnt -> staged data visible
    short8 af[MI], bfv[NI];
#pragma unroll
    for (int mi = 0; mi < MI; mi++)
      af[mi] = *(const short8*)&sm.st[(wr * MI + mi) * 512 + lo];
#pragma unroll
    for (int ni = 0; ni < NI; ni++)
      bfv[ni] = *(const short8*)&sm.st[(NSUB_A + wc * NI + ni) * 512 + lo];
#pragma unroll
    for (int mi = 0; mi < MI; mi++)
#pragma unroll
      for (int ni = 0; ni < NI; ni++)
        acc[mi][ni] = __builtin_amdgcn_mfma_f32_16x16x32_bf16(af[mi], bfv[ni], acc[mi][ni], 0, 0, 0);
  }

  __syncthreads();  // all LDS staging reads done before union reuse

  if constexpr (MODE == 0) {
    // fused logits stats: per (row, bn) -> top6 (value, global col) + (max, sumexp)
    float* pt6v = p1; float* pt6i_f = p2; float* pmx = p3; float* pse = p4;
    int* pt6i = (int*)pt6i_f;
#pragma unroll
    for (int ph = 0; ph < 2; ph++) {     // 32 rows per phase
#pragma unroll
      for (int mi2 = 0; mi2 < 2; mi2++) {
        int mi = ph * 2 + mi2;
#pragma unroll
        for (int ni = 0; ni < 2; ni++)
#pragma unroll
          for (int rr = 0; rr < 4; rr++)
            sm.ep.ct[(mi2 * 16 + quad * 4 + rr) * 133 + wave * 32 + ni * 16 + l16] =
                acc[mi][ni][rr] * INV_BETA;
      }
      __syncthreads();
      {
        int srow = t & 31, sseg = t >> 5;   // 8 segs x 16 cols
        float vv[16];
        const float* basep = &sm.ep.ct[srow * 133 + sseg * 16];
#pragma unroll
        for (int i = 0; i < 16; i++) vv[i] = basep[i];
        float v[6]; int vi[6];
#pragma unroll
        for (int j = 0; j < 6; j++) { v[j] = NEG_INF; vi[j] = 0x7fffffff; }
        int gcol0 = bn * 128 + sseg * 16;
#pragma unroll
        for (int i = 0; i < 16; i++) ins6i(vv[i], gcol0 + i, v, vi);
        float mloc = v[0];
        float se = 0.f;
#pragma unroll
        for (int i = 0; i < 16; i++) se += expf(vv[i] - mloc);
        int slot = srow * 8 + sseg;
#pragma unroll
        for (int j = 0; j < 6; j++) { sm.ep.p6v[slot * 6 + j] = v[j]; sm.ep.p6i[slot * 6 + j] = vi[j]; }
        sm.ep.ms[slot * 2] = mloc; sm.ep.ms[slot * 2 + 1] = se;
      }
      __syncthreads();
      if (t < 32) {
        float v[6]; int vi[6];
#pragma unroll
        for (int j = 0; j < 6; j++) { v[j] = NEG_INF; vi[j] = 0x7fffffff; }
        float M = NEG_INF, S = 0.f;
#pragma unroll
        for (int s = 0; s < 8; s++) {
          int slot = t * 8 + s;
#pragma unroll
          for (int j = 0; j < 6; j++) ins6i(sm.ep.p6v[slot * 6 + j], sm.ep.p6i[slot * 6 + j], v, vi);
          float mo = sm.ep.ms[slot * 2], so = sm.ep.ms[slot * 2 + 1];
          float Mn = fmaxf(M, mo);
          S = S * expf(M - Mn) + so * expf(mo - Mn);
          M = Mn;
        }
        int rowg = bm * 64 + ph * 32 + t;
        size_t base = ((size_t)rowg * NBLK + bn);
#pragma unroll
        for (int j = 0; j < 6; j++) { pt6v[base * 6 + j] = v[j]; pt6i[base * 6 + j] = vi[j]; }
        pmx[base] = M; pse[base] = S;
      }
      __syncthreads();
    }
  } else {
    float* part6 = p1;
#pragma unroll
    for (int ph = 0; ph < 4; ph++) {       // 32 tile-rows per phase
      int phwr = ph >> 1, phmi0 = (ph & 1) * 2;
      if (wr == phwr) {
#pragma unroll
        for (int mi2 = 0; mi2 < 2; mi2++) {
          int mi = phmi0 + mi2;
#pragma unroll
          for (int ni = 0; ni < 4; ni++)
#pragma unroll
            for (int rr = 0; rr < 4; rr++)
              sm.ep.ct[(mi2 * 16 + quad * 4 + rr) * 133 + wc * 64 + ni * 16 + l16] =
                  acc[mi][ni][rr];
        }
      }
      __syncthreads();
      {
        int srow = t & 31, sseg = t >> 5;   // 8 segs x 16 cols
        float v[6] = {NEG_INF, NEG_INF, NEG_INF, NEG_INF, NEG_INF, NEG_INF};
        const float* basep = &sm.ep.ct[srow * 133 + sseg * 16];
#pragma unroll
        for (int i = 0; i < 16; i++) ins6(basep[i], v);
#pragma unroll
        for (int j = 0; j < 6; j++) sm.ep.p6[srow * 49 + sseg * 6 + j] = v[j];
      }
      __syncthreads();
      if (t < 32) {
        float v[6] = {NEG_INF, NEG_INF, NEG_INF, NEG_INF, NEG_INF, NEG_INF};
        const float* pp = &sm.ep.p6[t * 49];
        for (int i = 0; i < 48; i++) ins6(pp[i], v);
        int rg = bm * 128 + ph * 32 + t;
        float* dst = part6 + ((size_t)rg * NBLK + bn) * 6;
#pragma unroll
        for (int j = 0; j < 6; j++) dst[j] = v[j];
      }
      __syncthreads();
    }
  }
}

// one wave per logit row: merge 128 per-block partials -> global top6 + lse
__global__ __launch_bounds__(256) void mergestats_kernel(
    const float* __restrict__ pt6v, const int* __restrict__ pt6i,
    const float* __restrict__ pmx, const float* __restrict__ pse,
    float* __restrict__ topv, int* __restrict__ topi, float* __restrict__ lse) {
  int gid = blockIdx.x * 256 + threadIdx.x;
  int m = gid >> 6, lane = gid & 63;
  if (m >= NB) return;
  float v[6]; int vi[6];
#pragma unroll
  for (int j = 0; j < 6; j++) { v[j] = NEG_INF; vi[j] = 0x7fffffff; }
  size_t rb = (size_t)m * NBLK;
#pragma unroll
  for (int a = 0; a < 12; a++) {        // 768 entries / 64 lanes
    int e = lane + a * 64;
    ins6i(pt6v[rb * 6 + e], pt6i[rb * 6 + e], v, vi);
  }
  float M = pmx[rb + lane], S = pse[rb + lane];
  {
    float mo = pmx[rb + lane + 64], so = pse[rb + lane + 64];
    float Mn = fmaxf(M, mo);
    S = S * expf(M - Mn) + so * expf(mo - Mn);
    M = Mn;
  }
#pragma unroll
  for (int off = 32; off > 0; off >>= 1) {
    float ov[6]; int oi[6];
#pragma unroll
    for (int j = 0; j < 6; j++) { ov[j] = __shfl_xor(v[j], off, 64); oi[j] = __shfl_xor(vi[j], off, 64); }
#pragma unroll
    for (int j = 0; j < 6; j++) ins6i(ov[j], oi[j], v, vi);
    float oM = __shfl_xor(M, off, 64), oS = __shfl_xor(S, off, 64);
    float Mn = fmaxf(M, oM);
    S = S * expf(M - Mn) + oS * expf(oM - Mn);
    M = Mn;
  }
  if (lane == 0) {
    lse[m] = M + logf(S);
#pragma unroll
    for (int j = 0; j < 6; j++) { topv[m * 6 + j] = v[j]; topi[m * 6 + j] = vi[j]; }
  }
}

// w < NR2: sa[w] = em[topi[w]] . em[anchor];  w in [NR2, NR2+NB): tl[m] = 20 * x[m].em[tgt[m]]
__global__ __launch_bounds__(256) void sa_kernel(const float* __restrict__ em,
                                                 const float* __restrict__ x,
                                                 const int* __restrict__ topi,
                                                 const int* __restrict__ targets,
                                                 float* __restrict__ sa,
                                                 float* __restrict__ tl) {
  int gid = blockIdx.x * 256 + threadIdx.x;
  int w = gid >> 6, lane = gid & 63;
  if (w >= NR2 + NB) return;
  const float* ei; const float* ea;
  if (w < NR2) {
    int m = w / 6;
    ei = em + (size_t)topi[w] * DIMK;
    ea = em + (size_t)topi[m * 6] * DIMK;
  } else {
    int m = w - NR2;
    ei = x + (size_t)m * DIMK;
    ea = em + (size_t)targets[m] * DIMK;
  }
  float s = 0.f;
  for (int d = lane; d < DIMK; d += 64) s += ei[d] * ea[d];
#pragma unroll
  for (int off = 32; off > 0; off >>= 1) s += __shfl_down(s, off, 64);
  if (lane == 0) {
    if (w < NR2) sa[w] = s;
    else tl[w - NR2] = s * INV_BETA;
  }
}

// recip[r] = 1 iff anchor-sim >= 6th-largest of sims row r
// == (count of partial-top6 values strictly greater than sa) < 6
__global__ __launch_bounds__(256) void stage2_kernel(const float* __restrict__ part6,
                                                     const float* __restrict__ sa,
                                                     int* __restrict__ recip) {
  int gid = blockIdx.x * 256 + threadIdx.x;
  int w = gid >> 6, lane = gid & 63;
  if (w >= NR2) return;
  float s = sa[w];
  const float* p = part6 + (size_t)w * (NBLK * 6);
  int cnt = 0;
  for (int i = lane; i < NBLK * 6; i += 64) cnt += (p[i] > s) ? 1 : 0;
#pragma unroll
  for (int off = 32; off > 0; off >>= 1) cnt += __shfl_down(cnt, off, 64);
  if (lane == 0) recip[w] = (cnt < 6) ? 1 : 0;
}

__global__ __launch_bounds__(256) void final_kernel(
    const float* __restrict__ tl_arr, const float* __restrict__ topv,
    const int* __restrict__ topi, const float* __restrict__ lse_arr,
    const int* __restrict__ recip, const int* __restrict__ targets,
    float* __restrict__ out) {
  int m = threadIdx.x;
  float lse = lse_arr[m];
  int tgt = targets[m];
  float tl = tl_arr[m];
  float beta = 0.f, Ps = 0.f, nbp = 0.f;
  bool tin = false;
#pragma unroll
  for (int k = 0; k < 6; k++) {
    int idx = topi[m * 6 + k]; float v = topv[m * 6 + k];
    float p = expf(v - lse);
    if (idx == tgt) { tin = true; beta += (lse - v); Ps += p; }
    else if (recip[m * 6 + k]) { beta += 0.5f * (lse - v); Ps += p; nbp += p; }
  }
  if (!tin) { beta += (lse - tl); Ps += expf(tl - lse); }
  float alpha = 9.2103404f * (1.f - Ps) + 0.6931472f * nbp;
  __shared__ float sA[256], sB2[256];
  sA[m] = alpha; sB2[m] = beta;
  __syncthreads();
  for (int s = 128; s > 0; s >>= 1) {
    if (m < s) { sA[m] += sA[m + s]; sB2[m] += sB2[m + s]; }
    __syncthreads();
  }
  if (m == 0) { out[0] = 0.05f * sA[0] / 256.f; out[1] = sB2[0] / 256.f; }
}

extern "C" void kernel_launch(void* const* d_in, const int* in_sizes, int n_in,
                              void* d_out, int out_size, void* d_ws, size_t ws_size,
                              hipStream_t stream) {
  const float* x = (const float*)d_in[0];
  const float* em = (const float*)d_in[1];
  const int* targets = (const int*)d_in[2];
  char* ws = (char*)d_ws;
  unsigned short* em_bf = (unsigned short*)ws;                 // 67108864 B
  unsigned short* x_bf  = (unsigned short*)(ws + 67108864);    // 1048576 B
  float* pt6v   = (float*)(ws + 68157440);                     // 786432 B
  float* pt6i_f = (float*)(ws + 68943872);                     // 786432 B
  float* pmx    = (float*)(ws + 69730304);                     // 131072 B
  float* pse    = (float*)(ws + 69861376);                     // 131072 B
  float* part6  = (float*)(ws + 69992448);                     // 4718592 B
  float* topv   = (float*)(ws + 74711040);                     // 6144 B
  int*   topi   = (int*)  (ws + 74717184);                     // 6144 B
  float* lse    = (float*)(ws + 74723328);                     // 1024 B
  float* sa     = (float*)(ws + 74724352);                     // 6144 B
  int*   recip  = (int*)  (ws + 74730496);                     // 6144 B
  float* tl     = (float*)(ws + 74736640);                     // 1024 B

  cvt_kernel<<<dim3(32768), dim3(256), 0, stream>>>(em, em_bf, NEMB * DIMK / 4);
  cvt_kernel<<<dim3(512), dim3(256), 0, stream>>>(x, x_bf, NB * DIMK / 4);
  gemm_kernel<0><<<dim3(128, 4), dim3(256), 0, stream>>>(x_bf, em_bf, (const int*)nullptr,
                                                         pt6v, pt6i_f, pmx, pse);
  mergestats_kernel<<<dim3(64), dim3(256), 0, stream>>>(pt6v, (const int*)pt6i_f, pmx, pse,
                                                        topv, topi, lse);
  sa_kernel<<<dim3(448), dim3(256), 0, stream>>>(em, x, topi, targets, sa, tl);
  gemm_kernel<1><<<dim3(128, 12), dim3(256), 0, stream>>>(em_bf, em_bf, topi,
                                                          part6, (float*)nullptr,
                                                          (float*)nullptr, (float*)nullptr);
  stage2_kernel<<<dim3(384), dim3(256), 0, stream>>>(part6, sa, recip);
  final_kernel<<<dim3(1), dim3(256), 0, stream>>>(tl, topv, topi, lse, recip, targets,
                                                  (float*)d_out);
}